// Round 9
// baseline (144.387 us; speedup 1.0000x reference)
//
#include <hip/hip_runtime.h>
#include <math.h>

// Problem constants
constexpr int R_ = 8;
constexpr int B_ = 16;
constexpr int D_ = 32;
constexpr int H_ = 128;
constexpr int N_ = 2048;
constexpr int F_ = 256;
constexpr int O_ = 64;               // 2*D
constexpr float HLP_ = 0.9189385332046727f;

typedef float f32x4 __attribute__((ext_vector_type(4)));
typedef short bf16x8 __attribute__((ext_vector_type(8)));
typedef unsigned uint32x4 __attribute__((ext_vector_type(4)));

// Pack two fp32 -> one dword of two bf16 (round-half-up, v_perm for hi halves).
__device__ __forceinline__ unsigned pk2(float lo, float hi) {
    unsigned a = __builtin_bit_cast(unsigned, lo) + 0x8000u;
    unsigned b = __builtin_bit_cast(unsigned, hi) + 0x8000u;
    return __builtin_amdgcn_perm(b, a, 0x07060302);   // {a.b2,a.b3,b.b2,b.b3}
}

// ---------------------------------------------------------------------------
// R9: R8 structure + 2 waves/SIMD (the R6-R8 plateau was 1 wave/SIMD latency
// exposure: Occ 10.7%, Mfma 8.7%, VALU 19% -> 72% idle).
// 512 blocks = 128 networks x 4 N-slices; 256 threads = 4 waves;
// __launch_bounds__(256,2) -> 2 blocks/CU (2 waves/SIMD), VGPR cap 256
// (measured 200 in R8). LDS 52 KB/block so 2 blocks fit (104 <= 160 KB).
//
// Phase 1 (7 barriers): stage W*M slabs via double-buffered LDS; every wave
//   reads all 56 A-frags into registers (224 VGPR):
//   A-frag (mt,kt), lane (q=lane>>4,c=lane&15), j: Wm[kt*32+q*8+j][mt*16+c].
//   region_idx is arange(F).reshape(R,D) -> x "gather" is two float4 loads.
//   W3 columns PERMUTED (R6-R8 validated): dest pair-slot (q,mt3,rr) holds
//   source d = q*8+mt3*2+rr, so epilogue x comes from the lane's own loads.
// Phase 2 (ZERO barriers): 4 passes x 2 tiles of 16 samples per wave;
//   h1/h2 transpose through per-wave LDS scratch (single-buffered, 8 KB/wave;
//   DS ops are in-order per wave -> race-free without barriers).
// ---------------------------------------------------------------------------
__global__ __launch_bounds__(256, 2)
void flow_all(const float* __restrict__ x,
              const float* __restrict__ W1, const float* __restrict__ W2,
              const float* __restrict__ W3,
              const float* __restrict__ M1, const float* __restrict__ M2,
              const float* __restrict__ M3,
              const int* __restrict__ ridx,
              float* __restrict__ out)
{
    __shared__ __align__(16) unsigned short stg[2][5120];   // 20 KB staging
    __shared__ __align__(16) unsigned short hws[4][4096];   // 32 KB (8 KB/wave)

    const int bid = blockIdx.x;
    const int rb  = bid >> 2;            // network 0..127
    const int sl  = bid & 3;             // N-slice (512 samples)
    const int r   = rb >> 4;

    const int t    = threadIdx.x;
    const int lane = t & 63;
    const int w    = t >> 6;             // wave 0..3
    const int q    = lane >> 4;
    const int c    = lane & 15;

    unsigned short* hwp = hws[w];

    // lane's base sample row; wave w owns rows [sl*512 + w*128, +128)
    const int nbase = sl * 512 + w * 128 + c;
    // contiguous feature base for this lane's d-octet (region_idx is arange)
    const int xoff = r * 32 + q * 8;

    auto xload = [&](int row, float* g) {
        const float* p0 = x + (size_t)row * F_ + xoff;
        float4 f0 = *(const float4*)p0;
        float4 f1 = *(const float4*)(p0 + 4);
        g[0] = f0.x; g[1] = f0.y; g[2] = f0.z; g[3] = f0.w;
        g[4] = f1.x; g[5] = f1.y; g[6] = f1.z; g[7] = f1.w;
    };

    // prefetch pass-0 rows (2 tiles) before weight packing
    float gA[8], gB[8];
    xload(nbase, gA);
    xload(nbase + 16, gB);

    // ---- phase 1: pack W*M -> register A-frags (staged via LDS) ----
    bf16x8 a1[8], a2[4][8], a3[4][4];
    {
        const float* W1b = W1 + (size_t)rb * 32 * 128;
        const float* M1b = M1 + (size_t)rb * 32 * 128;
        const float* W2b = W2 + (size_t)rb * 128 * 128;
        const float* M2s = M2;           // M2 identical across all networks
        const float* W3b = W3 + (size_t)rb * 128 * 64;
        const float* M3b = M3 + (size_t)rb * 128 * 64;

        const int pm  = t & 127, pkh = t >> 7;   // 128-wide slabs
        const int qm  = t & 63,  qk  = t >> 6;   // 64-wide superslabs
        // W3 column permutation (dest col -> source col)
        int osrc;
        {
            int dp = qm >> 1, pb = qm & 1;
            int dsrc = ((dp >> 1) & 3) * 8 + (dp >> 3) * 2 + (dp & 1);
            osrc = dsrc * 2 + pb;
        }

        float wv[2][16], mv[2][16];
        auto slab_load = [&](int s, float* wvv, float* mvv) {
            if (s == 0) {
                const float* wp = W1b + (size_t)(pkh * 16) * 128 + pm;
                const float* mp = M1b + (size_t)(pkh * 16) * 128 + pm;
#pragma unroll
                for (int e = 0; e < 16; ++e) { wvv[e] = wp[(size_t)e * 128]; mvv[e] = mp[(size_t)e * 128]; }
            } else if (s <= 4) {
                const float* wp = W2b + (size_t)((s - 1) * 32 + pkh * 16) * 128 + pm;
                const float* mp = M2s + (size_t)((s - 1) * 32 + pkh * 16) * 128 + pm;
#pragma unroll
                for (int e = 0; e < 16; ++e) { wvv[e] = wp[(size_t)e * 128]; mvv[e] = mp[(size_t)e * 128]; }
            } else {
                int ss = s - 5;
                const float* wp = W3b + (size_t)(ss * 64 + qk * 16) * 64 + osrc;
                const float* mp = M3b + (size_t)(ss * 64 + qk * 16) * 64 + osrc;
#pragma unroll
                for (int e = 0; e < 16; ++e) { wvv[e] = wp[(size_t)e * 64]; mvv[e] = mp[(size_t)e * 64]; }
            }
        };
        auto slab_store = [&](int s, const float* wvv, const float* mvv) {
            unsigned u[8];
#pragma unroll
            for (int e2 = 0; e2 < 8; ++e2)
                u[e2] = pk2(wvv[2 * e2] * mvv[2 * e2], wvv[2 * e2 + 1] * mvv[2 * e2 + 1]);
            uint32x4 ulo = {u[0], u[1], u[2], u[3]};
            uint32x4 uhi = {u[4], u[5], u[6], u[7]};
            unsigned short* st = stg[s & 1];
            if (s <= 4) {                // st[col*40 + k], k 0..31
                *(uint32x4*)&st[pm * 40 + pkh * 16]     = ulo;
                *(uint32x4*)&st[pm * 40 + pkh * 16 + 8] = uhi;
            } else {                     // st[col*72 + k], k 0..63
                *(uint32x4*)&st[qm * 72 + qk * 16]     = ulo;
                *(uint32x4*)&st[qm * 72 + qk * 16 + 8] = uhi;
            }
        };

        slab_load(0, wv[0], mv[0]);
#pragma unroll
        for (int s = 0; s < 7; ++s) {
            if (s < 6) slab_load(s + 1, wv[(s + 1) & 1], mv[(s + 1) & 1]);
            slab_store(s, wv[s & 1], mv[s & 1]);
            __syncthreads();
            const unsigned short* st = stg[s & 1];
            if (s == 0) {
#pragma unroll
                for (int mt = 0; mt < 8; ++mt)
                    a1[mt] = *(const bf16x8*)&st[(mt * 16 + c) * 40 + q * 8];
            } else if (s <= 4) {
#pragma unroll
                for (int mt = 0; mt < 8; ++mt)
                    a2[s - 1][mt] = *(const bf16x8*)&st[(mt * 16 + c) * 40 + q * 8];
            } else {
                int ss = s - 5;
#pragma unroll
                for (int mt3 = 0; mt3 < 4; ++mt3) {
                    a3[ss * 2 + 0][mt3] = *(const bf16x8*)&st[(mt3 * 16 + c) * 72 + 0  + q * 8];
                    a3[ss * 2 + 1][mt3] = *(const bf16x8*)&st[(mt3 * 16 + c) * 72 + 32 + q * 8];
                }
            }
        }
    }

    // h-store: C-layout quad -> B-frag layout (relu + bf16), b64 write.
    auto hstore = [&](int tau, int mt, const f32x4& v) {
        int ktw = mt >> 1;
        int qw  = (mt & 1) * 2 + (q >> 1);
        int j0  = (q & 1) * 4;
        unsigned lo = pk2(fmaxf(v[0], 0.f), fmaxf(v[1], 0.f));
        unsigned hi = pk2(fmaxf(v[2], 0.f), fmaxf(v[3], 0.f));
        *(uint2*)&hwp[(((tau * 4 + ktw) * 64) + qw * 16 + c) * 8 + j0] = make_uint2(lo, hi);
    };

    const f32x4 z = {0.f, 0.f, 0.f, 0.f};

    // ---- phase 2: 4 passes x 2 tiles, zero barriers, weights in regs ----
#pragma unroll 1
    for (int p = 0; p < 4; ++p) {
        float xA[8], xB[8];
#pragma unroll
        for (int j = 0; j < 8; ++j) { xA[j] = gA[j]; xB[j] = gB[j]; }
        uint32x4 uA = {pk2(xA[0], xA[1]), pk2(xA[2], xA[3]), pk2(xA[4], xA[5]), pk2(xA[6], xA[7])};
        uint32x4 uB = {pk2(xB[0], xB[1]), pk2(xB[2], xB[3]), pk2(xB[4], xB[5]), pk2(xB[6], xB[7])};
        bf16x8 xbA = __builtin_bit_cast(bf16x8, uA);
        bf16x8 xbB = __builtin_bit_cast(bf16x8, uB);

        // GEMM1 (K=32): 16 MFMA, A-frags in regs
        {
            f32x4 accA[8], accB[8];
#pragma unroll
            for (int mt = 0; mt < 8; ++mt) {
                accA[mt] = __builtin_amdgcn_mfma_f32_16x16x32_bf16(a1[mt], xbA, z, 0, 0, 0);
                accB[mt] = __builtin_amdgcn_mfma_f32_16x16x32_bf16(a1[mt], xbB, z, 0, 0, 0);
            }
#pragma unroll
            for (int mt = 0; mt < 8; ++mt) { hstore(0, mt, accA[mt]); hstore(1, mt, accB[mt]); }
        }

        // prefetch next pass's rows (latency hidden under GEMM2/3)
        if (p < 3) {
            xload(nbase + (p + 1) * 32, gA);
            xload(nbase + (p + 1) * 32 + 16, gB);
        }

        // GEMM2 (K=128): 64 MFMA, 8 b128 LDS reads
        {
            f32x4 c2A[8], c2B[8];
#pragma unroll
            for (int mt = 0; mt < 8; ++mt) { c2A[mt] = z; c2B[mt] = z; }
#pragma unroll
            for (int kt = 0; kt < 4; ++kt) {
                bf16x8 bA = *(const bf16x8*)&hwp[((0 * 4 + kt) * 64 + lane) * 8];
                bf16x8 bB = *(const bf16x8*)&hwp[((1 * 4 + kt) * 64 + lane) * 8];
#pragma unroll
                for (int mt = 0; mt < 8; ++mt) {
                    c2A[mt] = __builtin_amdgcn_mfma_f32_16x16x32_bf16(a2[kt][mt], bA, c2A[mt], 0, 0, 0);
                    c2B[mt] = __builtin_amdgcn_mfma_f32_16x16x32_bf16(a2[kt][mt], bB, c2B[mt], 0, 0, 0);
                }
            }
#pragma unroll
            for (int mt = 0; mt < 8; ++mt) { hstore(0, mt, c2A[mt]); hstore(1, mt, c2B[mt]); }
        }

        // GEMM3 (K=128, O=64 permuted): 32 MFMA + MAF epilogue
        {
            f32x4 c3A[4], c3B[4];
#pragma unroll
            for (int mt3 = 0; mt3 < 4; ++mt3) { c3A[mt3] = z; c3B[mt3] = z; }
#pragma unroll
            for (int kt = 0; kt < 4; ++kt) {
                bf16x8 bA = *(const bf16x8*)&hwp[((0 * 4 + kt) * 64 + lane) * 8];
                bf16x8 bB = *(const bf16x8*)&hwp[((1 * 4 + kt) * 64 + lane) * 8];
#pragma unroll
                for (int mt3 = 0; mt3 < 4; ++mt3) {
                    c3A[mt3] = __builtin_amdgcn_mfma_f32_16x16x32_bf16(a3[kt][mt3], bA, c3A[mt3], 0, 0, 0);
                    c3B[mt3] = __builtin_amdgcn_mfma_f32_16x16x32_bf16(a3[kt][mt3], bB, c3B[mt3], 0, 0, 0);
                }
            }
            // epilogue: slot o = mt3*16+q*4+reg; rr=reg>>1 -> source
            // d = q*8 + mt3*2 + rr -> x is the lane's own xA/xB[mt3*2+rr]
            float llA = 0.f, llB = 0.f;
#pragma unroll
            for (int mt3 = 0; mt3 < 4; ++mt3) {
#pragma unroll
                for (int rr = 0; rr < 2; ++rr) {
                    float shA = c3A[mt3][rr * 2], lsA = c3A[mt3][rr * 2 + 1];
                    float shB = c3B[mt3][rr * 2], lsB = c3B[mt3][rr * 2 + 1];
                    float u0 = (xA[mt3 * 2 + rr] - shA) * __expf(-lsA);
                    float u1 = (xB[mt3 * 2 + rr] - shB) * __expf(-lsB);
                    llA += fmaf(-0.5f * u0, u0, -HLP_ - lsA);
                    llB += fmaf(-0.5f * u1, u1, -HLP_ - lsB);
                }
            }
            llA += __shfl_xor(llA, 16, 64);  llA += __shfl_xor(llA, 32, 64);
            llB += __shfl_xor(llB, 16, 64);  llB += __shfl_xor(llB, 32, 64);
            if (q == 0) {
                int n = nbase + p * 32;
                out[(size_t)n * 128 + rb]        = llA;
                out[(size_t)(n + 16) * 128 + rb] = llB;
            }
        }
    }
}

extern "C" void kernel_launch(void* const* d_in, const int* in_sizes, int n_in,
                              void* d_out, int out_size, void* d_ws, size_t ws_size,
                              hipStream_t stream) {
    const float* x   = (const float*)d_in[0];
    const float* W1  = (const float*)d_in[1];
    const float* W2  = (const float*)d_in[2];
    const float* W3  = (const float*)d_in[3];
    const float* M1  = (const float*)d_in[4];
    const float* M2  = (const float*)d_in[5];
    const float* M3  = (const float*)d_in[6];
    const int*  ridx = (const int*)d_in[7];
    float* out = (float*)d_out;

    flow_all<<<dim3(512), dim3(256), 0, stream>>>(x, W1, W2, W3, M1, M2, M3, ridx, out);
}

// Round 10
// 108.712 us; speedup vs baseline: 1.3282x; 1.3282x over previous
//
#include <hip/hip_runtime.h>
#include <math.h>

// Problem constants
constexpr int R_ = 8;
constexpr int B_ = 16;
constexpr int D_ = 32;
constexpr int H_ = 128;
constexpr int N_ = 2048;
constexpr int F_ = 256;
constexpr int O_ = 64;               // 2*D
constexpr float HLP_ = 0.9189385332046727f;

typedef float f32x4 __attribute__((ext_vector_type(4)));
typedef short bf16x8 __attribute__((ext_vector_type(8)));
typedef unsigned uint32x4 __attribute__((ext_vector_type(4)));

// Pack two fp32 -> one dword of two bf16 (round-half-up, v_perm for hi halves).
__device__ __forceinline__ unsigned pk2(float lo, float hi) {
    unsigned a = __builtin_bit_cast(unsigned, lo) + 0x8000u;
    unsigned b = __builtin_bit_cast(unsigned, hi) + 0x8000u;
    return __builtin_amdgcn_perm(b, a, 0x07060302);   // {a.b2,a.b3,b.b2,b.b3}
}

// ---------------------------------------------------------------------------
// R10: hybrid weight placement to get 2 waves/SIMD WITHOUT spills.
//   R8: all weights in regs -> 1 wave/SIMD, 61 us, 72% idle.
//   R9: launch_bounds(256,2) + weights in regs -> spills (VGPR 128, 66 MB
//       scratch writes), 77 us. Conclusion: regs-only and 2 waves/SIMD are
//       mutually exclusive; W2 (128 regs of frags) must live in LDS.
//
// 512 blocks = 128 networks x 4 N-slices; 256 threads = 4 waves;
// __launch_bounds__(256,2): peak demand ~233 regs < 256 -> no spill.
// LDS: WA2 (W2 A-frags) 32 KB + union{stg 20 KB (phase1) | hws 32 KB (phase2)}
//      = 64 KB/block -> 2 blocks/CU (128 <= 160 KB).
//
// Phase 1: W1 -> regs a1[8] and W3 -> regs a3[4][4] via stg transpose tiles
//   (3 barriers); W2*M2 packed DIRECTLY global->WA2 in A-frag layout (thread
//   (pm,pkh) owns frag (kt, mt=pm>>4), lanes (q=pkh*2{,+1}, c=pm&15): two
//   b128 writes, no staging). M2 is identical across networks (broadcast).
//   W3 columns PERMUTED (R6-R9 validated): dest pair-slot (q,mt3,rr) holds
//   source d = q*8+mt3*2+rr -> epilogue x comes from the lane's own loads.
// Phase 2 (ZERO barriers): 4 passes x 2 tiles x 16 samples per wave;
//   GEMM2 streams W2 frags from WA2 (contiguous b128, conflict-free, each
//   frag feeds 2 MFMAs); h1/h2 transpose via per-wave LDS scratch (DS ops
//   are in-order per wave -> race-free).
// region_idx is arange(F).reshape(R,D) -> x load is two float4s, no gather.
// ---------------------------------------------------------------------------
__global__ __launch_bounds__(256, 2)
void flow_all(const float* __restrict__ x,
              const float* __restrict__ W1, const float* __restrict__ W2,
              const float* __restrict__ W3,
              const float* __restrict__ M1, const float* __restrict__ M2,
              const float* __restrict__ M3,
              const int* __restrict__ ridx,
              float* __restrict__ out)
{
    __shared__ __align__(16) unsigned short WA2[16384];  // 32 KB: W2 A-frags
    __shared__ __align__(16) unsigned short uni[16384];  // 32 KB: stg | hws

    const int bid = blockIdx.x;
    const int rb  = bid >> 2;            // network 0..127
    const int sl  = bid & 3;             // N-slice (512 samples)
    const int r   = rb >> 4;

    const int t    = threadIdx.x;
    const int lane = t & 63;
    const int w    = t >> 6;             // wave 0..3
    const int q    = lane >> 4;
    const int c    = lane & 15;

    unsigned short* stg0 = uni;          // phase-1 staging (5120 shorts)
    unsigned short* stg1 = uni + 5120;
    unsigned short* hwp  = uni + w * 4096;   // phase-2 per-wave scratch

    // lane's base sample row; wave w owns rows [sl*512 + w*128, +128)
    const int nbase = sl * 512 + w * 128 + c;
    const int xoff  = r * 32 + q * 8;    // contiguous feature base

    auto xload = [&](int row, float* g) {
        const float* p0 = x + (size_t)row * F_ + xoff;
        float4 f0 = *(const float4*)p0;
        float4 f1 = *(const float4*)(p0 + 4);
        g[0] = f0.x; g[1] = f0.y; g[2] = f0.z; g[3] = f0.w;
        g[4] = f1.x; g[5] = f1.y; g[6] = f1.z; g[7] = f1.w;
    };

    // ---- phase 1: W1/W3 -> register frags; W2 -> WA2 frags ----
    bf16x8 a1[8], a3[4][4];
    {
        const float* W1b = W1 + (size_t)rb * 32 * 128;
        const float* M1b = M1 + (size_t)rb * 32 * 128;
        const float* W2b = W2 + (size_t)rb * 128 * 128;
        const float* M2s = M2;           // M2 identical across all networks
        const float* W3b = W3 + (size_t)rb * 128 * 64;
        const float* M3b = M3 + (size_t)rb * 128 * 64;

        const int pm = t & 127, pkh = t >> 7;   // 128-wide slabs
        const int qm = t & 63,  qk  = t >> 6;   // 64-wide superslabs
        // W3 column permutation (dest col -> source col), R6-R9 validated
        int osrc;
        {
            int dp = qm >> 1, pb = qm & 1;
            int dsrc = ((dp >> 1) & 3) * 8 + (dp >> 3) * 2 + (dp & 1);
            osrc = dsrc * 2 + pb;
        }

        float wv[2][16], mv[2][16];
        // slabs: 0 = W1; 1..4 = W2 kt 0..3; 5,6 = W3 halves
        auto slab_load = [&](int s, float* wvv, float* mvv) {
            if (s == 0) {
                const float* wp = W1b + (size_t)(pkh * 16) * 128 + pm;
                const float* mp = M1b + (size_t)(pkh * 16) * 128 + pm;
#pragma unroll
                for (int e = 0; e < 16; ++e) { wvv[e] = wp[(size_t)e * 128]; mvv[e] = mp[(size_t)e * 128]; }
            } else if (s <= 4) {
                const float* wp = W2b + (size_t)((s - 1) * 32 + pkh * 16) * 128 + pm;
                const float* mp = M2s + (size_t)((s - 1) * 32 + pkh * 16) * 128 + pm;
#pragma unroll
                for (int e = 0; e < 16; ++e) { wvv[e] = wp[(size_t)e * 128]; mvv[e] = mp[(size_t)e * 128]; }
            } else {
                int ss = s - 5;
                const float* wp = W3b + (size_t)(ss * 64 + qk * 16) * 64 + osrc;
                const float* mp = M3b + (size_t)(ss * 64 + qk * 16) * 64 + osrc;
#pragma unroll
                for (int e = 0; e < 16; ++e) { wvv[e] = wp[(size_t)e * 64]; mvv[e] = mp[(size_t)e * 64]; }
            }
        };
        auto pack8 = [&](const float* wvv, const float* mvv, unsigned* u) {
#pragma unroll
            for (int e2 = 0; e2 < 8; ++e2)
                u[e2] = pk2(wvv[2 * e2] * mvv[2 * e2], wvv[2 * e2 + 1] * mvv[2 * e2 + 1]);
        };
        auto store_stg128 = [&](unsigned short* st, const float* wvv, const float* mvv) {
            unsigned u[8]; pack8(wvv, mvv, u);
            *(uint32x4*)&st[pm * 40 + pkh * 16]     = (uint32x4){u[0], u[1], u[2], u[3]};
            *(uint32x4*)&st[pm * 40 + pkh * 16 + 8] = (uint32x4){u[4], u[5], u[6], u[7]};
        };
        auto store_stg64 = [&](unsigned short* st, const float* wvv, const float* mvv) {
            unsigned u[8]; pack8(wvv, mvv, u);
            *(uint32x4*)&st[qm * 72 + qk * 16]     = (uint32x4){u[0], u[1], u[2], u[3]};
            *(uint32x4*)&st[qm * 72 + qk * 16 + 8] = (uint32x4){u[4], u[5], u[6], u[7]};
        };
        // direct A-frag pack: thread holds cols m=pm, rows klocal=pkh*16+e.
        // frag (kt, mt=pm>>4); element j=e&7, lane = (pkh*2 + (e>>3))*16 + (pm&15)
        auto store_wa2 = [&](int kt, const float* wvv, const float* mvv) {
            unsigned u[8]; pack8(wvv, mvv, u);
            int mt = pm >> 4, cc = pm & 15, q0 = pkh * 2;
            *(uint32x4*)&WA2[(((kt * 8 + mt) * 64) + q0 * 16 + cc) * 8]       = (uint32x4){u[0], u[1], u[2], u[3]};
            *(uint32x4*)&WA2[(((kt * 8 + mt) * 64) + (q0 + 1) * 16 + cc) * 8] = (uint32x4){u[4], u[5], u[6], u[7]};
        };

        slab_load(0, wv[0], mv[0]);
        slab_load(1, wv[1], mv[1]);
        // s0: W1 -> stg0 -> a1
        store_stg128(stg0, wv[0], mv[0]);
        __syncthreads();
#pragma unroll
        for (int mt = 0; mt < 8; ++mt)
            a1[mt] = *(const bf16x8*)&stg0[(mt * 16 + c) * 40 + q * 8];
        // s1..4: W2 -> WA2 (no barriers; covered by the s5 barrier)
        slab_load(2, wv[0], mv[0]);
        store_wa2(0, wv[1], mv[1]);
        slab_load(3, wv[1], mv[1]);
        store_wa2(1, wv[0], mv[0]);
        slab_load(4, wv[0], mv[0]);
        store_wa2(2, wv[1], mv[1]);
        slab_load(5, wv[1], mv[1]);
        store_wa2(3, wv[0], mv[0]);
        slab_load(6, wv[0], mv[0]);
        // s5: W3 k0..63 -> stg1 -> a3[0..1]
        store_stg64(stg1, wv[1], mv[1]);
        __syncthreads();
#pragma unroll
        for (int mt3 = 0; mt3 < 4; ++mt3) {
            a3[0][mt3] = *(const bf16x8*)&stg1[(mt3 * 16 + c) * 72 + 0  + q * 8];
            a3[1][mt3] = *(const bf16x8*)&stg1[(mt3 * 16 + c) * 72 + 32 + q * 8];
        }
        // s6: W3 k64..127 -> stg0 (safe: s5 barrier is after all a1 reads)
        store_stg64(stg0, wv[0], mv[0]);
        __syncthreads();
#pragma unroll
        for (int mt3 = 0; mt3 < 4; ++mt3) {
            a3[2][mt3] = *(const bf16x8*)&stg0[(mt3 * 16 + c) * 72 + 0  + q * 8];
            a3[3][mt3] = *(const bf16x8*)&stg0[(mt3 * 16 + c) * 72 + 32 + q * 8];
        }
    }
    __syncthreads();   // uni switches role stg -> hws; WA2 fully written

    // h-store: C-layout quad -> B-frag layout (relu + bf16), b64 write.
    auto hstore = [&](int tau, int mt, const f32x4& v) {
        int ktw = mt >> 1;
        int qw  = (mt & 1) * 2 + (q >> 1);
        int j0  = (q & 1) * 4;
        unsigned lo = pk2(fmaxf(v[0], 0.f), fmaxf(v[1], 0.f));
        unsigned hi = pk2(fmaxf(v[2], 0.f), fmaxf(v[3], 0.f));
        *(uint2*)&hwp[(((tau * 4 + ktw) * 64) + qw * 16 + c) * 8 + j0] = make_uint2(lo, hi);
    };

    const f32x4 z = {0.f, 0.f, 0.f, 0.f};

    // ---- phase 2: 4 passes x 2 tiles, zero barriers ----
#pragma unroll 1
    for (int p = 0; p < 4; ++p) {
        float xA[8], xB[8];
        xload(nbase + p * 32,      xA);
        xload(nbase + p * 32 + 16, xB);
        uint32x4 uA = {pk2(xA[0], xA[1]), pk2(xA[2], xA[3]), pk2(xA[4], xA[5]), pk2(xA[6], xA[7])};
        uint32x4 uB = {pk2(xB[0], xB[1]), pk2(xB[2], xB[3]), pk2(xB[4], xB[5]), pk2(xB[6], xB[7])};
        bf16x8 xbA = __builtin_bit_cast(bf16x8, uA);
        bf16x8 xbB = __builtin_bit_cast(bf16x8, uB);

        // GEMM1 (K=32): 16 MFMA, a1 in regs
        {
            f32x4 accA[8], accB[8];
#pragma unroll
            for (int mt = 0; mt < 8; ++mt) {
                accA[mt] = __builtin_amdgcn_mfma_f32_16x16x32_bf16(a1[mt], xbA, z, 0, 0, 0);
                accB[mt] = __builtin_amdgcn_mfma_f32_16x16x32_bf16(a1[mt], xbB, z, 0, 0, 0);
            }
#pragma unroll
            for (int mt = 0; mt < 8; ++mt) { hstore(0, mt, accA[mt]); hstore(1, mt, accB[mt]); }
        }

        // GEMM2 (K=128): 64 MFMA; W2 frags streamed from WA2 (b128, 2 MFMA/read)
        {
            f32x4 c2A[8], c2B[8];
#pragma unroll
            for (int mt = 0; mt < 8; ++mt) { c2A[mt] = z; c2B[mt] = z; }
#pragma unroll
            for (int kt = 0; kt < 4; ++kt) {
                bf16x8 bA = *(const bf16x8*)&hwp[((0 * 4 + kt) * 64 + lane) * 8];
                bf16x8 bB = *(const bf16x8*)&hwp[((1 * 4 + kt) * 64 + lane) * 8];
                bf16x8 a2t[8];
#pragma unroll
                for (int mt = 0; mt < 8; ++mt)
                    a2t[mt] = *(const bf16x8*)&WA2[((kt * 8 + mt) * 64 + lane) * 8];
#pragma unroll
                for (int mt = 0; mt < 8; ++mt) {
                    c2A[mt] = __builtin_amdgcn_mfma_f32_16x16x32_bf16(a2t[mt], bA, c2A[mt], 0, 0, 0);
                    c2B[mt] = __builtin_amdgcn_mfma_f32_16x16x32_bf16(a2t[mt], bB, c2B[mt], 0, 0, 0);
                }
            }
#pragma unroll
            for (int mt = 0; mt < 8; ++mt) { hstore(0, mt, c2A[mt]); hstore(1, mt, c2B[mt]); }
        }

        // GEMM3 (K=128, O=64 permuted): 32 MFMA, a3 in regs + MAF epilogue
        {
            f32x4 c3A[4], c3B[4];
#pragma unroll
            for (int mt3 = 0; mt3 < 4; ++mt3) { c3A[mt3] = z; c3B[mt3] = z; }
#pragma unroll
            for (int kt = 0; kt < 4; ++kt) {
                bf16x8 bA = *(const bf16x8*)&hwp[((0 * 4 + kt) * 64 + lane) * 8];
                bf16x8 bB = *(const bf16x8*)&hwp[((1 * 4 + kt) * 64 + lane) * 8];
#pragma unroll
                for (int mt3 = 0; mt3 < 4; ++mt3) {
                    c3A[mt3] = __builtin_amdgcn_mfma_f32_16x16x32_bf16(a3[kt][mt3], bA, c3A[mt3], 0, 0, 0);
                    c3B[mt3] = __builtin_amdgcn_mfma_f32_16x16x32_bf16(a3[kt][mt3], bB, c3B[mt3], 0, 0, 0);
                }
            }
            // epilogue: slot o = mt3*16+q*4+reg; rr=reg>>1 -> source
            // d = q*8 + mt3*2 + rr -> x is the lane's own xA/xB[mt3*2+rr]
            float llA = 0.f, llB = 0.f;
#pragma unroll
            for (int mt3 = 0; mt3 < 4; ++mt3) {
#pragma unroll
                for (int rr = 0; rr < 2; ++rr) {
                    float shA = c3A[mt3][rr * 2], lsA = c3A[mt3][rr * 2 + 1];
                    float shB = c3B[mt3][rr * 2], lsB = c3B[mt3][rr * 2 + 1];
                    float u0 = (xA[mt3 * 2 + rr] - shA) * __expf(-lsA);
                    float u1 = (xB[mt3 * 2 + rr] - shB) * __expf(-lsB);
                    llA += fmaf(-0.5f * u0, u0, -HLP_ - lsA);
                    llB += fmaf(-0.5f * u1, u1, -HLP_ - lsB);
                }
            }
            llA += __shfl_xor(llA, 16, 64);  llA += __shfl_xor(llA, 32, 64);
            llB += __shfl_xor(llB, 16, 64);  llB += __shfl_xor(llB, 32, 64);
            if (q == 0) {
                int n = nbase + p * 32;
                out[(size_t)n * 128 + rb]        = llA;
                out[(size_t)(n + 16) * 128 + rb] = llB;
            }
        }
    }
}

extern "C" void kernel_launch(void* const* d_in, const int* in_sizes, int n_in,
                              void* d_out, int out_size, void* d_ws, size_t ws_size,
                              hipStream_t stream) {
    const float* x   = (const float*)d_in[0];
    const float* W1  = (const float*)d_in[1];
    const float* W2  = (const float*)d_in[2];
    const float* W3  = (const float*)d_in[3];
    const float* M1  = (const float*)d_in[4];
    const float* M2  = (const float*)d_in[5];
    const float* M3  = (const float*)d_in[6];
    const int*  ridx = (const int*)d_in[7];
    float* out = (float*)d_out;

    flow_all<<<dim3(512), dim3(256), 0, stream>>>(x, W1, W2, W3, M1, M2, M3, ridx, out);
}

// Round 11
// 108.352 us; speedup vs baseline: 1.3326x; 1.0033x over previous
//
#include <hip/hip_runtime.h>
#include <math.h>

// Problem constants
constexpr int R_ = 8;
constexpr int B_ = 16;
constexpr int D_ = 32;
constexpr int H_ = 128;
constexpr int N_ = 2048;
constexpr int F_ = 256;
constexpr int O_ = 64;               // 2*D
constexpr float HLP_ = 0.9189385332046727f;

typedef float f32x4 __attribute__((ext_vector_type(4)));
typedef short bf16x8 __attribute__((ext_vector_type(8)));
typedef unsigned uint32x4 __attribute__((ext_vector_type(4)));

// Pack two fp32 -> one dword of two bf16 (round-half-up, v_perm for hi halves).
__device__ __forceinline__ unsigned pk2(float lo, float hi) {
    unsigned a = __builtin_bit_cast(unsigned, lo) + 0x8000u;
    unsigned b = __builtin_bit_cast(unsigned, hi) + 0x8000u;
    return __builtin_amdgcn_perm(b, a, 0x07060302);   // {a.b2,a.b3,b.b2,b.b3}
}

// ---------------------------------------------------------------------------
// R11: one phase-1 per CU at 2 waves/SIMD.
//   Cross-round evidence: R8 (1 blk/CU, 1 wave/SIMD) == R10 (2 blk/CU,
//   2 waves/SIMD, TWO phase-1s/CU) == ~109-112 us. Phase-1 redundancy scales
//   with blocks/CU and cancels TLP gains. Fix: 256 blocks x 512 threads
//   (8 waves) = 1 block/CU, 2 waves/SIMD, ONE phase-1 per CU.
//
// __launch_bounds__(512,2): VGPR cap 256, measured demand ~200 -> no spill.
// LDS: WA2 32 KB + stg 20 KB + hws 64 KB (8 KB/wave) = 116 KB (1 block/CU).
//
// Phase 1: W1 -> regs a1[8], W3 -> regs a3[4][4] (via stg transpose tiles);
//   W2*M2 packed DIRECTLY global->WA2 in A-frag layout (512-thread mapping:
//   thread (pm,pkh) holds rows pkh*8+e, col pm -> frag (kt,mt=pm>>4),
//   lane pkh*16+(pm&15), j=e: ONE b128 write). M2 identical across networks.
//   A-frag (mt,kt), lane (q,c), j: Wm[kt*32+q*8+j][mt*16+c].
//   W3 columns PERMUTED (R6-R10 validated): dest pair-slot (q,mt3,rr) holds
//   source d = q*8+mt3*2+rr -> epilogue x comes from the lane's own loads.
// Phase 2 (ZERO barriers): 4 passes x 2 tiles x 16 samples per wave, with
//   pass-ahead x prefetch; h1/h2 transpose via per-wave LDS scratch (DS ops
//   in-order per wave -> race-free); GEMM2 streams W2 frags from WA2.
// region_idx is arange(F).reshape(R,D) -> x load is two float4s, no gather.
// ---------------------------------------------------------------------------
__global__ __launch_bounds__(512, 2)
void flow_all(const float* __restrict__ x,
              const float* __restrict__ W1, const float* __restrict__ W2,
              const float* __restrict__ W3,
              const float* __restrict__ M1, const float* __restrict__ M2,
              const float* __restrict__ M3,
              const int* __restrict__ ridx,
              float* __restrict__ out)
{
    __shared__ __align__(16) unsigned short WA2[16384];     // 32 KB: W2 A-frags
    __shared__ __align__(16) unsigned short stg[2][5120];   // 20 KB staging
    __shared__ __align__(16) unsigned short hws[8][4096];   // 64 KB (8 KB/wave)

    const int bid = blockIdx.x;
    const int rb  = bid >> 1;            // network 0..127
    const int hf  = bid & 1;             // half of N
    const int r   = rb >> 4;

    const int t    = threadIdx.x;
    const int lane = t & 63;
    const int w    = t >> 6;             // wave 0..7
    const int q    = lane >> 4;
    const int c    = lane & 15;

    unsigned short* hwp = hws[w];

    // lane's base sample row; wave w owns rows [hf*1024 + w*128, +128)
    const int nbase = hf * 1024 + w * 128 + c;
    const int xoff  = r * 32 + q * 8;    // contiguous feature base

    auto xload = [&](int row, float* g) {
        const float* p0 = x + (size_t)row * F_ + xoff;
        float4 f0 = *(const float4*)p0;
        float4 f1 = *(const float4*)(p0 + 4);
        g[0] = f0.x; g[1] = f0.y; g[2] = f0.z; g[3] = f0.w;
        g[4] = f1.x; g[5] = f1.y; g[6] = f1.z; g[7] = f1.w;
    };

    // prefetch pass-0 rows (2 tiles) before weight packing
    float gA[8], gB[8];
    xload(nbase, gA);
    xload(nbase + 16, gB);

    // ---- phase 1: W1/W3 -> register frags; W2 -> WA2 frags ----
    bf16x8 a1[8], a3[4][4];
    {
        const float* W1b = W1 + (size_t)rb * 32 * 128;
        const float* M1b = M1 + (size_t)rb * 32 * 128;
        const float* W2b = W2 + (size_t)rb * 128 * 128;
        const float* M2s = M2;           // M2 identical across all networks
        const float* W3b = W3 + (size_t)rb * 128 * 64;
        const float* M3b = M3 + (size_t)rb * 128 * 64;

        const int pm = t & 127, pkh = t >> 7;   // 128-wide slabs: col, row-octet (0..3)
        const int qm = t & 63,  qk  = t >> 6;   // 64-wide superslabs: col, row-octet (0..7)
        // W3 column permutation (dest col -> source col), R6-R10 validated
        int osrc;
        {
            int dp = qm >> 1, pb = qm & 1;
            int dsrc = ((dp >> 1) & 3) * 8 + (dp >> 3) * 2 + (dp & 1);
            osrc = dsrc * 2 + pb;
        }

        float wv[2][8], mv[2][8];
        // slabs: 0 = W1; 1..4 = W2 kt 0..3; 5,6 = W3 halves (64 rows each)
        auto slab_load = [&](int s, float* wvv, float* mvv) {
            if (s == 0) {
                const float* wp = W1b + (size_t)(pkh * 8) * 128 + pm;
                const float* mp = M1b + (size_t)(pkh * 8) * 128 + pm;
#pragma unroll
                for (int e = 0; e < 8; ++e) { wvv[e] = wp[(size_t)e * 128]; mvv[e] = mp[(size_t)e * 128]; }
            } else if (s <= 4) {
                const float* wp = W2b + (size_t)((s - 1) * 32 + pkh * 8) * 128 + pm;
                const float* mp = M2s + (size_t)((s - 1) * 32 + pkh * 8) * 128 + pm;
#pragma unroll
                for (int e = 0; e < 8; ++e) { wvv[e] = wp[(size_t)e * 128]; mvv[e] = mp[(size_t)e * 128]; }
            } else {
                int ss = s - 5;
                const float* wp = W3b + (size_t)(ss * 64 + qk * 8) * 64 + osrc;
                const float* mp = M3b + (size_t)(ss * 64 + qk * 8) * 64 + osrc;
#pragma unroll
                for (int e = 0; e < 8; ++e) { wvv[e] = wp[(size_t)e * 64]; mvv[e] = mp[(size_t)e * 64]; }
            }
        };
        auto pack4 = [&](const float* wvv, const float* mvv, unsigned* u) {
#pragma unroll
            for (int e2 = 0; e2 < 4; ++e2)
                u[e2] = pk2(wvv[2 * e2] * mvv[2 * e2], wvv[2 * e2 + 1] * mvv[2 * e2 + 1]);
        };
        auto store_stg128 = [&](unsigned short* st, const float* wvv, const float* mvv) {
            unsigned u[4]; pack4(wvv, mvv, u);
            *(uint32x4*)&st[pm * 40 + pkh * 8] = (uint32x4){u[0], u[1], u[2], u[3]};
        };
        auto store_stg64 = [&](unsigned short* st, const float* wvv, const float* mvv) {
            unsigned u[4]; pack4(wvv, mvv, u);
            *(uint32x4*)&st[qm * 72 + qk * 8] = (uint32x4){u[0], u[1], u[2], u[3]};
        };
        // direct A-frag pack: rows klocal = pkh*8+e -> q = pkh, j = e;
        // frag (kt, mt = pm>>4), lane = pkh*16 + (pm&15): ONE b128 write.
        auto store_wa2 = [&](int kt, const float* wvv, const float* mvv) {
            unsigned u[4]; pack4(wvv, mvv, u);
            int mt = pm >> 4, cc = pm & 15;
            *(uint32x4*)&WA2[(((kt * 8 + mt) * 64) + pkh * 16 + cc) * 8] = (uint32x4){u[0], u[1], u[2], u[3]};
        };

        slab_load(0, wv[0], mv[0]);
        slab_load(1, wv[1], mv[1]);
        // s0: W1 -> stg0 -> a1
        store_stg128(stg[0], wv[0], mv[0]);
        __syncthreads();
#pragma unroll
        for (int mt = 0; mt < 8; ++mt)
            a1[mt] = *(const bf16x8*)&stg[0][(mt * 16 + c) * 40 + q * 8];
        // s1..4: W2 -> WA2 (no barriers; covered by s5's barrier)
        slab_load(2, wv[0], mv[0]);
        store_wa2(0, wv[1], mv[1]);
        slab_load(3, wv[1], mv[1]);
        store_wa2(1, wv[0], mv[0]);
        slab_load(4, wv[0], mv[0]);
        store_wa2(2, wv[1], mv[1]);
        slab_load(5, wv[1], mv[1]);
        store_wa2(3, wv[0], mv[0]);
        slab_load(6, wv[0], mv[0]);
        // s5: W3 k0..63 -> stg1 -> a3[0..1]
        store_stg64(stg[1], wv[1], mv[1]);
        __syncthreads();
#pragma unroll
        for (int mt3 = 0; mt3 < 4; ++mt3) {
            a3[0][mt3] = *(const bf16x8*)&stg[1][(mt3 * 16 + c) * 72 + 0  + q * 8];
            a3[1][mt3] = *(const bf16x8*)&stg[1][(mt3 * 16 + c) * 72 + 32 + q * 8];
        }
        // s6: W3 k64..127 -> stg0 (safe: all a1 reads precede the s5 barrier)
        store_stg64(stg[0], wv[0], mv[0]);
        __syncthreads();
#pragma unroll
        for (int mt3 = 0; mt3 < 4; ++mt3) {
            a3[2][mt3] = *(const bf16x8*)&stg[0][(mt3 * 16 + c) * 72 + 0  + q * 8];
            a3[3][mt3] = *(const bf16x8*)&stg[0][(mt3 * 16 + c) * 72 + 32 + q * 8];
        }
    }
    __syncthreads();   // WA2 fully written, stg dead

    // h-store: C-layout quad -> B-frag layout (relu + bf16), b64 write.
    auto hstore = [&](int tau, int mt, const f32x4& v) {
        int ktw = mt >> 1;
        int qw  = (mt & 1) * 2 + (q >> 1);
        int j0  = (q & 1) * 4;
        unsigned lo = pk2(fmaxf(v[0], 0.f), fmaxf(v[1], 0.f));
        unsigned hi = pk2(fmaxf(v[2], 0.f), fmaxf(v[3], 0.f));
        *(uint2*)&hwp[(((tau * 4 + ktw) * 64) + qw * 16 + c) * 8 + j0] = make_uint2(lo, hi);
    };

    const f32x4 z = {0.f, 0.f, 0.f, 0.f};

    // ---- phase 2: 4 passes x 2 tiles, zero barriers ----
#pragma unroll 1
    for (int p = 0; p < 4; ++p) {
        float xA[8], xB[8];
#pragma unroll
        for (int j = 0; j < 8; ++j) { xA[j] = gA[j]; xB[j] = gB[j]; }
        uint32x4 uA = {pk2(xA[0], xA[1]), pk2(xA[2], xA[3]), pk2(xA[4], xA[5]), pk2(xA[6], xA[7])};
        uint32x4 uB = {pk2(xB[0], xB[1]), pk2(xB[2], xB[3]), pk2(xB[4], xB[5]), pk2(xB[6], xB[7])};
        bf16x8 xbA = __builtin_bit_cast(bf16x8, uA);
        bf16x8 xbB = __builtin_bit_cast(bf16x8, uB);

        // GEMM1 (K=32): 16 MFMA, a1 in regs
        {
            f32x4 accA[8], accB[8];
#pragma unroll
            for (int mt = 0; mt < 8; ++mt) {
                accA[mt] = __builtin_amdgcn_mfma_f32_16x16x32_bf16(a1[mt], xbA, z, 0, 0, 0);
                accB[mt] = __builtin_amdgcn_mfma_f32_16x16x32_bf16(a1[mt], xbB, z, 0, 0, 0);
            }
#pragma unroll
            for (int mt = 0; mt < 8; ++mt) { hstore(0, mt, accA[mt]); hstore(1, mt, accB[mt]); }
        }

        // pass-ahead x prefetch (latency hidden under GEMM2/3)
        if (p < 3) {
            xload(nbase + (p + 1) * 32, gA);
            xload(nbase + (p + 1) * 32 + 16, gB);
        }

        // GEMM2 (K=128): 64 MFMA; W2 frags streamed from WA2 (b128, 2 MFMA/read)
        {
            f32x4 c2A[8], c2B[8];
#pragma unroll
            for (int mt = 0; mt < 8; ++mt) { c2A[mt] = z; c2B[mt] = z; }
#pragma unroll
            for (int kt = 0; kt < 4; ++kt) {
                bf16x8 bA = *(const bf16x8*)&hwp[((0 * 4 + kt) * 64 + lane) * 8];
                bf16x8 bB = *(const bf16x8*)&hwp[((1 * 4 + kt) * 64 + lane) * 8];
                bf16x8 a2t[8];
#pragma unroll
                for (int mt = 0; mt < 8; ++mt)
                    a2t[mt] = *(const bf16x8*)&WA2[((kt * 8 + mt) * 64 + lane) * 8];
#pragma unroll
                for (int mt = 0; mt < 8; ++mt) {
                    c2A[mt] = __builtin_amdgcn_mfma_f32_16x16x32_bf16(a2t[mt], bA, c2A[mt], 0, 0, 0);
                    c2B[mt] = __builtin_amdgcn_mfma_f32_16x16x32_bf16(a2t[mt], bB, c2B[mt], 0, 0, 0);
                }
            }
#pragma unroll
            for (int mt = 0; mt < 8; ++mt) { hstore(0, mt, c2A[mt]); hstore(1, mt, c2B[mt]); }
        }

        // GEMM3 (K=128, O=64 permuted): 32 MFMA, a3 in regs + MAF epilogue
        {
            f32x4 c3A[4], c3B[4];
#pragma unroll
            for (int mt3 = 0; mt3 < 4; ++mt3) { c3A[mt3] = z; c3B[mt3] = z; }
#pragma unroll
            for (int kt = 0; kt < 4; ++kt) {
                bf16x8 bA = *(const bf16x8*)&hwp[((0 * 4 + kt) * 64 + lane) * 8];
                bf16x8 bB = *(const bf16x8*)&hwp[((1 * 4 + kt) * 64 + lane) * 8];
#pragma unroll
                for (int mt3 = 0; mt3 < 4; ++mt3) {
                    c3A[mt3] = __builtin_amdgcn_mfma_f32_16x16x32_bf16(a3[kt][mt3], bA, c3A[mt3], 0, 0, 0);
                    c3B[mt3] = __builtin_amdgcn_mfma_f32_16x16x32_bf16(a3[kt][mt3], bB, c3B[mt3], 0, 0, 0);
                }
            }
            // epilogue: slot o = mt3*16+q*4+reg; rr=reg>>1 -> source
            // d = q*8 + mt3*2 + rr -> x is the lane's own xA/xB[mt3*2+rr]
            float llA = 0.f, llB = 0.f;
#pragma unroll
            for (int mt3 = 0; mt3 < 4; ++mt3) {
#pragma unroll
                for (int rr = 0; rr < 2; ++rr) {
                    float shA = c3A[mt3][rr * 2], lsA = c3A[mt3][rr * 2 + 1];
                    float shB = c3B[mt3][rr * 2], lsB = c3B[mt3][rr * 2 + 1];
                    float u0 = (xA[mt3 * 2 + rr] - shA) * __expf(-lsA);
                    float u1 = (xB[mt3 * 2 + rr] - shB) * __expf(-lsB);
                    llA += fmaf(-0.5f * u0, u0, -HLP_ - lsA);
                    llB += fmaf(-0.5f * u1, u1, -HLP_ - lsB);
                }
            }
            llA += __shfl_xor(llA, 16, 64);  llA += __shfl_xor(llA, 32, 64);
            llB += __shfl_xor(llB, 16, 64);  llB += __shfl_xor(llB, 32, 64);
            if (q == 0) {
                int n = nbase + p * 32;
                out[(size_t)n * 128 + rb]        = llA;
                out[(size_t)(n + 16) * 128 + rb] = llB;
            }
        }
    }
}

extern "C" void kernel_launch(void* const* d_in, const int* in_sizes, int n_in,
                              void* d_out, int out_size, void* d_ws, size_t ws_size,
                              hipStream_t stream) {
    const float* x   = (const float*)d_in[0];
    const float* W1  = (const float*)d_in[1];
    const float* W2  = (const float*)d_in[2];
    const float* W3  = (const float*)d_in[3];
    const float* M1  = (const float*)d_in[4];
    const float* M2  = (const float*)d_in[5];
    const float* M3  = (const float*)d_in[6];
    const int*  ridx = (const int*)d_in[7];
    float* out = (float*)d_out;

    flow_all<<<dim3(256), dim3(512), 0, stream>>>(x, W1, W2, W3, M1, M2, M3, ridx, out);
}